// Round 2
// baseline (1530.744 us; speedup 1.0000x reference)
//
#include <hip/hip_runtime.h>

#define N_NODES 100000
#define N_EDGES 1200000
#define R_REL 3
#define RN (R_REL * N_NODES)   // 300000
#define RE (R_REL * N_EDGES)   // 3600000

typedef unsigned int uint;

__device__ __forceinline__ float bcast(float v, int l) {
  return __int_as_float(__builtin_amdgcn_readlane(__float_as_int(v), l));
}
__device__ __forceinline__ uint bf16r(float x) {  // round-to-nearest-even bf16
  uint u = __float_as_uint(x);
  return (u + 0x7fffu + ((u >> 16) & 1u)) >> 16;
}
__device__ __forceinline__ float lo16(uint u) { return __uint_as_float(u << 16); }
__device__ __forceinline__ float hi16(uint u) { return __uint_as_float(u & 0xffff0000u); }

// ---------------- CSR build ----------------
__global__ void k_zero(int* p, int n) {
  int i = blockIdx.x * 256 + threadIdx.x;
  if (i < n) p[i] = 0;
}

__global__ void k_count(const int* __restrict__ dst, int* __restrict__ deg) {
  int i = blockIdx.x * 256 + threadIdx.x;
  if (i < RE) {
    int r = i / N_EDGES;
    atomicAdd(&deg[r * N_NODES + dst[i]], 1);
  }
}

__global__ void k_scan1(const int* __restrict__ deg, int* __restrict__ P,
                        int* __restrict__ bsums) {
  __shared__ int sd[256];
  int t = threadIdx.x;
  int base = blockIdx.x * 2048 + t * 8;
  int v[8];
  int tot = 0;
#pragma unroll
  for (int q = 0; q < 8; q++) {
    v[q] = (base + q < RN) ? deg[base + q] : 0;
    tot += v[q];
  }
  sd[t] = tot;
  __syncthreads();
  for (int off = 1; off < 256; off <<= 1) {
    int x = (t >= off) ? sd[t - off] : 0;
    __syncthreads();
    sd[t] += x;
    __syncthreads();
  }
  int run = sd[t] - tot;
#pragma unroll
  for (int q = 0; q < 8; q++) {
    if (base + q < RN) P[base + q] = run;
    run += v[q];
  }
  if (t == 255) bsums[blockIdx.x] = sd[255];
}

__global__ void k_scan2(const int* __restrict__ bsums, int* __restrict__ boffs, int nb) {
  __shared__ int sd[256];
  int t = threadIdx.x;
  int v = (t < nb) ? bsums[t] : 0;
  sd[t] = v;
  __syncthreads();
  for (int off = 1; off < 256; off <<= 1) {
    int x = (t >= off) ? sd[t - off] : 0;
    __syncthreads();
    sd[t] += x;
    __syncthreads();
  }
  if (t < nb) boffs[t] = sd[t] - v;
}

__global__ void k_scan3(int* __restrict__ P, int* __restrict__ cursor,
                        const int* __restrict__ boffs) {
  int i = blockIdx.x * 256 + threadIdx.x;
  if (i < RN) {
    int p = P[i] + boffs[i >> 11];
    P[i] = p;
    cursor[i] = p;
  }
}

__global__ void k_scatter(const int* __restrict__ src, const int* __restrict__ dst,
                          int* __restrict__ cursor, int* __restrict__ ssrc) {
  int i = blockIdx.x * 256 + threadIdx.x;
  if (i < RE) {
    int r = i / N_EDGES;
    int p = atomicAdd(&cursor[r * N_NODES + dst[i]], 1);
    ssrc[p] = src[i];
  }
}

// ---------------- node transforms ----------------
// pck[(r*N+n)*68 + c], c<64 : (bf16(hp_r[n][c])<<16) | bf16(es[n][c])
//                      c=64..67 : float bits of asrc[r][n][head]
__global__ __launch_bounds__(256) void k_node(
    const float* __restrict__ h, const float* __restrict__ d_w,
    const float* __restrict__ d_b, const float* __restrict__ w_w,
    const float* __restrict__ w_b, const float* __restrict__ atten_w,
    const float* __restrict__ atten_b, uint* __restrict__ pck,
    float* __restrict__ adst) {
  __shared__ float sW[4 * 4096];  // 64 KB: d_w, w_w[0..2], layout [m][k*64+c]
  int tid = threadIdx.x;
  for (int idx = tid; idx < 4096; idx += 256) {
    sW[idx] = d_w[idx];
    sW[4096 + idx] = w_w[idx];
    sW[8192 + idx] = w_w[4096 + idx];
    sW[12288 + idx] = w_w[8192 + idx];
  }
  __syncthreads();
  int lane = tid & 63, wid = tid >> 6;
  int wave = blockIdx.x * 4 + wid, nw = gridDim.x * 4;
  int k16 = lane & 15, hgrp = lane >> 4;
  float dbv = d_b[lane];
  float wbv0 = w_b[lane], wbv1 = w_b[64 + lane], wbv2 = w_b[128 + lane];
  float wa0[3], wa1[3], wa2[3], ab[3];
#pragma unroll
  for (int r = 0; r < 3; r++) {
    wa0[r] = atten_w[r * 48 + k16];
    wa1[r] = atten_w[r * 48 + 16 + k16];
    wa2[r] = atten_w[r * 48 + 32 + k16];
    ab[r] = atten_b[r];
  }
  for (int g = wave; g < N_NODES / 8; g += nw) {
    int n0 = g * 8;
    float hr[8];
#pragma unroll
    for (int i = 0; i < 8; i++) hr[i] = h[(n0 + i) * 64 + lane];
    float acc[8][4];
#pragma unroll
    for (int i = 0; i < 8; i++) {
      acc[i][0] = dbv; acc[i][1] = wbv0; acc[i][2] = wbv1; acc[i][3] = wbv2;
    }
#pragma unroll 4
    for (int k = 0; k < 64; k++) {
      float w0 = sW[k * 64 + lane];
      float w1 = sW[4096 + k * 64 + lane];
      float w2 = sW[8192 + k * 64 + lane];
      float w3 = sW[12288 + k * 64 + lane];
#pragma unroll
      for (int i = 0; i < 8; i++) {
        float a = bcast(hr[i], k);
        acc[i][0] += a * w0; acc[i][1] += a * w1;
        acc[i][2] += a * w2; acc[i][3] += a * w3;
      }
    }
#pragma unroll
    for (int i = 0; i < 8; i++) {
      int n = n0 + i;
      float esv = tanhf(2.f * acc[i][0]);
      uint esb = bf16r(esv);
#pragma unroll
      for (int r = 0; r < 3; r++) {
        float hpv = acc[i][1 + r];
        size_t row = (size_t)(r * N_NODES + n) * 68;
        pck[row + lane] = (bf16r(hpv) << 16) | esb;
        float cs = hpv * wa0[r] + esv * wa2[r];
        float cd = hpv * wa1[r];
#pragma unroll
        for (int m = 1; m < 16; m <<= 1) {
          cs += __shfl_xor(cs, m);
          cd += __shfl_xor(cd, m);
        }
        if (k16 == 0) {
          pck[row + 64 + hgrp] = __float_as_uint(cs + ab[r]);
          adst[(size_t)(r * N_NODES + n) * 4 + hgrp] = cd;
        }
      }
    }
  }
}

// ---------------- fused: per-dst softmax-aggregate + gate + final linear ----------------
__global__ __launch_bounds__(512) void k_fused(
    const uint* __restrict__ pck, const float* __restrict__ adst,
    const int* __restrict__ P, const int* __restrict__ ssrc,
    const float* __restrict__ beta, const float* __restrict__ lin_w,
    const float* __restrict__ lin_b, float* __restrict__ out) {
  // lin_w transposed + bf16-packed: sU[c*98 + jp] = (bf16(w[2jp+1][c])<<16)|bf16(w[2jp][c])
  __shared__ uint sU[64 * 98];  // 25088 B
  int tid = threadIdx.x;
  for (int idx = tid; idx < 96 * 64; idx += 512) {
    int c = idx & 63, jp = idx >> 6;
    float w0 = lin_w[(2 * jp) * 64 + c];
    float w1 = lin_w[(2 * jp + 1) * 64 + c];
    sU[c * 98 + jp] = (bf16r(w1) << 16) | bf16r(w0);
  }
  __syncthreads();
  int lane = tid & 63, wid = tid >> 6;
  int g = blockIdx.x * 8 + wid;  // 4 nodes per wave
  int hgrp = lane >> 4;
  float y0 = lin_b[lane];
  float y[4] = {y0, y0, y0, y0};
#pragma unroll
  for (int r = 0; r < 3; r++) {
    float hr[4];
    float b0 = beta[r * 128 + lane], b1 = beta[r * 128 + 64 + lane];
    int rbase = r * N_NODES;
    for (int i = 0; i < 4; i++) {
      int n = g * 4 + i;
      int idxrn = rbase + n;
      int beg = P[idxrn];
      int end = (idxrn + 1 < RN) ? P[idxrn + 1] : RE;
      float adh = adst[(size_t)idxrn * 4 + hgrp];
      float oacc = 0.f, eacc = 0.f, dsum = 0.f;
      int e = beg;
      for (; e + 2 <= end; e += 2) {
        int s0 = ssrc[e], s1 = ssrc[e + 1];
        const uint* r0 = pck + (size_t)(rbase + s0) * 68;
        const uint* r1 = pck + (size_t)(rbase + s1) * 68;
        uint pv0 = r0[lane];
        float a0 = __uint_as_float(r0[64 + hgrp]) + adh;
        uint pv1 = r1[lane];
        float a1 = __uint_as_float(r1[64 + hgrp]) + adh;
        a0 = a0 >= 0.f ? a0 : 0.01f * a0;
        a1 = a1 >= 0.f ? a1 : 0.01f * a1;
        float ex0 = __expf(a0), ex1 = __expf(a1);
        oacc += ex0 * hi16(pv0) + ex1 * hi16(pv1);
        eacc += lo16(pv0) + lo16(pv1);
        dsum += ex0 + ex1;
      }
      if (e < end) {
        int s0 = ssrc[e];
        const uint* r0 = pck + (size_t)(rbase + s0) * 68;
        uint pv0 = r0[lane];
        float a0 = __uint_as_float(r0[64 + hgrp]) + adh;
        a0 = a0 >= 0.f ? a0 : 0.01f * a0;
        float ex0 = __expf(a0);
        oacc += ex0 * hi16(pv0);
        eacc += lo16(pv0);
        dsum += ex0;
      }
      float ov = oacc / fmaxf(dsum, 1e-20f);
      float em = eacc / fmaxf((float)(end - beg), 1.f);
      float gc = em * b0 + ov * b1;
#pragma unroll
      for (int m = 1; m < 64; m <<= 1) gc += __shfl_xor(gc, m);
      float gt = 1.f / (1.f + __expf(-gc));
      float hpv = hi16(pck[(size_t)idxrn * 68 + lane]);  // self hp (bf16)
      hr[i] = gt * ov + (1.f - gt) * hpv;
    }
    const uint* wrow = &sU[lane * 98 + r * 32];
#pragma unroll
    for (int jp = 0; jp < 32; jp += 2) {
      uint2 wv = *reinterpret_cast<const uint2*>(wrow + jp);
      float w0 = lo16(wv.x), w1 = hi16(wv.x), w2 = lo16(wv.y), w3 = hi16(wv.y);
#pragma unroll
      for (int i = 0; i < 4; i++) {
        y[i] += bcast(hr[i], 2 * jp) * w0 + bcast(hr[i], 2 * jp + 1) * w1 +
                bcast(hr[i], 2 * jp + 2) * w2 + bcast(hr[i], 2 * jp + 3) * w3;
      }
    }
  }
#pragma unroll
  for (int i = 0; i < 4; i++) out[(size_t)(g * 4 + i) * 64 + lane] = y[i];
}

extern "C" void kernel_launch(void* const* d_in, const int* in_sizes, int n_in,
                              void* d_out, int out_size, void* d_ws, size_t ws_size,
                              hipStream_t stream) {
  const float* h = (const float*)d_in[0];
  const int* src = (const int*)d_in[1];
  const int* dst = (const int*)d_in[2];
  const float* d_w = (const float*)d_in[3];
  const float* d_b = (const float*)d_in[4];
  const float* w_w = (const float*)d_in[5];
  const float* w_b = (const float*)d_in[6];
  const float* atten_w = (const float*)d_in[7];
  const float* atten_b = (const float*)d_in[8];
  const float* beta = (const float*)d_in[9];
  const float* lin_w = (const float*)d_in[10];
  const float* lin_b = (const float*)d_in[11];
  float* out = (float*)d_out;

  uint* pck = (uint*)d_ws;                       // RN*68 uints
  float* adst = (float*)(pck + (size_t)RN * 68); // RN*4 floats
  int* deg = (int*)(adst + (size_t)RN * 4);      // RN
  int* P = deg + RN;                             // RN
  int* cursor = P + RN;                          // RN
  int* bsums = cursor + RN;                      // 256
  int* boffs = bsums + 256;                      // 256
  int* ssrc = boffs + 256;                       // RE

  int nb = (RN + 2047) / 2048;
  k_zero<<<(RN + 255) / 256, 256, 0, stream>>>(deg, RN);
  k_count<<<(RE + 255) / 256, 256, 0, stream>>>(dst, deg);
  k_scan1<<<nb, 256, 0, stream>>>(deg, P, bsums);
  k_scan2<<<1, 256, 0, stream>>>(bsums, boffs, nb);
  k_scan3<<<(RN + 255) / 256, 256, 0, stream>>>(P, cursor, boffs);
  k_scatter<<<(RE + 255) / 256, 256, 0, stream>>>(src, dst, cursor, ssrc);
  k_node<<<1024, 256, 0, stream>>>(h, d_w, d_b, w_w, w_b, atten_w, atten_b, pck, adst);
  k_fused<<<N_NODES / 32, 512, 0, stream>>>(pck, adst, P, ssrc, beta, lin_w, lin_b, out);
}

// Round 3
// 1497.416 us; speedup vs baseline: 1.0223x; 1.0223x over previous
//
#include <hip/hip_runtime.h>

#define N_NODES 100000
#define N_EDGES 1200000
#define R_REL 3
#define RN (R_REL * N_NODES)   // 300000
#define RE (R_REL * N_EDGES)   // 3600000

typedef unsigned int uint;

__device__ __forceinline__ float bcast(float v, int l) {
  return __int_as_float(__builtin_amdgcn_readlane(__float_as_int(v), l));
}
__device__ __forceinline__ uint bf16r(float x) {  // round-to-nearest-even bf16
  uint u = __float_as_uint(x);
  return (u + 0x7fffu + ((u >> 16) & 1u)) >> 16;
}
__device__ __forceinline__ float lo16(uint u) { return __uint_as_float(u << 16); }
__device__ __forceinline__ float hi16(uint u) { return __uint_as_float(u & 0xffff0000u); }

// ---------------- CSR build ----------------
__global__ void k_count(const int* __restrict__ dst, int* __restrict__ deg,
                        int* __restrict__ rank) {
  int i = blockIdx.x * 256 + threadIdx.x;
  if (i < RE) {
    int r = i / N_EDGES;
    rank[i] = atomicAdd(&deg[r * N_NODES + dst[i]], 1);
  }
}

__global__ void k_scan1(const int* __restrict__ deg, int* __restrict__ P,
                        int* __restrict__ bsums) {
  __shared__ int sd[256];
  int t = threadIdx.x;
  int base = blockIdx.x * 2048 + t * 8;
  int v[8];
  int tot = 0;
#pragma unroll
  for (int q = 0; q < 8; q++) {
    v[q] = (base + q < RN) ? deg[base + q] : 0;
    tot += v[q];
  }
  sd[t] = tot;
  __syncthreads();
  for (int off = 1; off < 256; off <<= 1) {
    int x = (t >= off) ? sd[t - off] : 0;
    __syncthreads();
    sd[t] += x;
    __syncthreads();
  }
  int run = sd[t] - tot;
#pragma unroll
  for (int q = 0; q < 8; q++) {
    if (base + q < RN) P[base + q] = run;
    run += v[q];
  }
  if (t == 255) bsums[blockIdx.x] = sd[255];
}

__global__ void k_scan2(const int* __restrict__ bsums, int* __restrict__ boffs, int nb) {
  __shared__ int sd[256];
  int t = threadIdx.x;
  int v = (t < nb) ? bsums[t] : 0;
  sd[t] = v;
  __syncthreads();
  for (int off = 1; off < 256; off <<= 1) {
    int x = (t >= off) ? sd[t - off] : 0;
    __syncthreads();
    sd[t] += x;
    __syncthreads();
  }
  if (t < nb) boffs[t] = sd[t] - v;
}

__global__ void k_scan3(int* __restrict__ P, const int* __restrict__ boffs) {
  int i = blockIdx.x * 256 + threadIdx.x;
  if (i < RN) P[i] += boffs[i >> 11];
}

__global__ void k_scatter(const int* __restrict__ src, const int* __restrict__ dst,
                          const int* __restrict__ rank, const int* __restrict__ P,
                          int* __restrict__ ssrc) {
  int i = blockIdx.x * 256 + threadIdx.x;
  if (i < RE) {
    int r = i / N_EDGES;
    ssrc[P[r * N_NODES + dst[i]] + rank[i]] = src[i];
  }
  if (i == 0) { ssrc[RE] = 0; ssrc[RE + 1] = 0; }  // prefetch pad
}

// ---------------- node transforms ----------------
// pck[(r*N+n)*64 + c] = (bf16(hp_r[n][c])<<16) | bf16(es[n][c])   (256B rows, aligned)
// asrc[(r*N+n)*4 + head], adst[(r*N+n)*4 + head] : fp32
__global__ __launch_bounds__(256) void k_node(
    const float* __restrict__ h, const float* __restrict__ d_w,
    const float* __restrict__ d_b, const float* __restrict__ w_w,
    const float* __restrict__ w_b, const float* __restrict__ atten_w,
    const float* __restrict__ atten_b, uint* __restrict__ pck,
    float* __restrict__ asrc, float* __restrict__ adst) {
  __shared__ float sW[4 * 4096];  // 64 KB: d_w, w_w[0..2], layout [m][k*64+c]
  int tid = threadIdx.x;
  for (int idx = tid; idx < 4096; idx += 256) {
    sW[idx] = d_w[idx];
    sW[4096 + idx] = w_w[idx];
    sW[8192 + idx] = w_w[4096 + idx];
    sW[12288 + idx] = w_w[8192 + idx];
  }
  __syncthreads();
  int lane = tid & 63, wid = tid >> 6;
  int wave = blockIdx.x * 4 + wid, nw = gridDim.x * 4;
  int k16 = lane & 15, hgrp = lane >> 4;
  float dbv = d_b[lane];
  float wbv0 = w_b[lane], wbv1 = w_b[64 + lane], wbv2 = w_b[128 + lane];
  float wa0[3], wa1[3], wa2[3], ab[3];
#pragma unroll
  for (int r = 0; r < 3; r++) {
    wa0[r] = atten_w[r * 48 + k16];
    wa1[r] = atten_w[r * 48 + 16 + k16];
    wa2[r] = atten_w[r * 48 + 32 + k16];
    ab[r] = atten_b[r];
  }
  for (int g = wave; g < N_NODES / 8; g += nw) {
    int n0 = g * 8;
    float hr[8];
#pragma unroll
    for (int i = 0; i < 8; i++) hr[i] = h[(n0 + i) * 64 + lane];
    float acc[8][4];
#pragma unroll
    for (int i = 0; i < 8; i++) {
      acc[i][0] = dbv; acc[i][1] = wbv0; acc[i][2] = wbv1; acc[i][3] = wbv2;
    }
#pragma unroll 4
    for (int k = 0; k < 64; k++) {
      float w0 = sW[k * 64 + lane];
      float w1 = sW[4096 + k * 64 + lane];
      float w2 = sW[8192 + k * 64 + lane];
      float w3 = sW[12288 + k * 64 + lane];
#pragma unroll
      for (int i = 0; i < 8; i++) {
        float a = bcast(hr[i], k);
        acc[i][0] += a * w0; acc[i][1] += a * w1;
        acc[i][2] += a * w2; acc[i][3] += a * w3;
      }
    }
#pragma unroll
    for (int i = 0; i < 8; i++) {
      int n = n0 + i;
      float esv = tanhf(2.f * acc[i][0]);
      uint esb = bf16r(esv);
#pragma unroll
      for (int r = 0; r < 3; r++) {
        float hpv = acc[i][1 + r];
        int idxrn = r * N_NODES + n;
        pck[(size_t)idxrn * 64 + lane] = (bf16r(hpv) << 16) | esb;
        float cs = hpv * wa0[r] + esv * wa2[r];
        float cd = hpv * wa1[r];
#pragma unroll
        for (int m = 1; m < 16; m <<= 1) {
          cs += __shfl_xor(cs, m);
          cd += __shfl_xor(cd, m);
        }
        if (k16 == 0) {
          asrc[(size_t)idxrn * 4 + hgrp] = cs + ab[r];
          adst[(size_t)idxrn * 4 + hgrp] = cd;
        }
      }
    }
  }
}

// ---------------- fused: per-dst softmax-aggregate + gate + final linear ----------------
__global__ __launch_bounds__(512, 8) void k_fused(
    const uint* __restrict__ pck, const float* __restrict__ asrc,
    const float* __restrict__ adst, const int* __restrict__ P,
    const int* __restrict__ ssrc, const float* __restrict__ beta,
    const float* __restrict__ lin_w, const float* __restrict__ lin_b,
    float* __restrict__ out) {
  // lin_w transposed + bf16-packed: sU[c*98 + jp] = (bf16(w[2jp+1][c])<<16)|bf16(w[2jp][c])
  __shared__ uint sU[64 * 98];  // 25088 B
  int tid = threadIdx.x;
  for (int idx = tid; idx < 96 * 64; idx += 512) {
    int c = idx & 63, jp = idx >> 6;
    float w0 = lin_w[(2 * jp) * 64 + c];
    float w1 = lin_w[(2 * jp + 1) * 64 + c];
    sU[c * 98 + jp] = (bf16r(w1) << 16) | bf16r(w0);
  }
  __syncthreads();
  int lane = tid & 63, wid = tid >> 6;
  int g = blockIdx.x * 8 + wid;  // 4 nodes per wave
  int hgrp = lane >> 4;
  float y0 = lin_b[lane];
  float y[4] = {y0, y0, y0, y0};
#pragma unroll
  for (int r = 0; r < 3; r++) {
    float hr[4];
    float b0 = beta[r * 128 + lane], b1 = beta[r * 128 + 64 + lane];
    int rbase = r * N_NODES;
    for (int i = 0; i < 4; i++) {
      int n = g * 4 + i;
      int idxrn = rbase + n;
      int beg = P[idxrn];
      int end = (idxrn + 1 < RN) ? P[idxrn + 1] : RE;
      float adh = adst[(size_t)idxrn * 4 + hgrp];
      float hpself = hi16(pck[(size_t)idxrn * 64 + lane]);  // early, hides latency
      float oacc = 0.f, eacc = 0.f, dsum = 0.f;
      // depth-2 pipeline; prefetch runs into the (contiguous) next segment harmlessly
      int sA = __builtin_amdgcn_readfirstlane(ssrc[beg]);
      int sB = __builtin_amdgcn_readfirstlane(ssrc[beg + 1]);
      uint pvA = pck[((size_t)(rbase + sA) << 6) + lane];
      float aA = asrc[((size_t)(rbase + sA) << 2) + hgrp];
      uint pvB = pck[((size_t)(rbase + sB) << 6) + lane];
      float aB = asrc[((size_t)(rbase + sB) << 2) + hgrp];
      for (int e = beg; e < end; ++e) {
        uint pv = pvA; float a = aA;
        pvA = pvB; aA = aB;
        int sC = __builtin_amdgcn_readfirstlane(ssrc[e + 2]);
        pvB = pck[((size_t)(rbase + sC) << 6) + lane];
        aB = asrc[((size_t)(rbase + sC) << 2) + hgrp];
        a += adh;
        a = a >= 0.f ? a : 0.01f * a;
        float ex = __expf(a);
        oacc += ex * hi16(pv);
        eacc += lo16(pv);
        dsum += ex;
      }
      float ov = oacc / fmaxf(dsum, 1e-20f);
      float em = eacc / fmaxf((float)(end - beg), 1.f);
      float gc = em * b0 + ov * b1;
#pragma unroll
      for (int m = 1; m < 64; m <<= 1) gc += __shfl_xor(gc, m);
      float gt = 1.f / (1.f + __expf(-gc));
      hr[i] = gt * ov + (1.f - gt) * hpself;
    }
    const uint* wrow = &sU[lane * 98 + r * 32];
#pragma unroll
    for (int jp = 0; jp < 32; jp += 2) {
      uint2 wv = *reinterpret_cast<const uint2*>(wrow + jp);
      float w0 = lo16(wv.x), w1 = hi16(wv.x), w2 = lo16(wv.y), w3 = hi16(wv.y);
#pragma unroll
      for (int i = 0; i < 4; i++) {
        y[i] += bcast(hr[i], 2 * jp) * w0 + bcast(hr[i], 2 * jp + 1) * w1 +
                bcast(hr[i], 2 * jp + 2) * w2 + bcast(hr[i], 2 * jp + 3) * w3;
      }
    }
  }
#pragma unroll
  for (int i = 0; i < 4; i++) out[(size_t)(g * 4 + i) * 64 + lane] = y[i];
}

extern "C" void kernel_launch(void* const* d_in, const int* in_sizes, int n_in,
                              void* d_out, int out_size, void* d_ws, size_t ws_size,
                              hipStream_t stream) {
  const float* h = (const float*)d_in[0];
  const int* src = (const int*)d_in[1];
  const int* dst = (const int*)d_in[2];
  const float* d_w = (const float*)d_in[3];
  const float* d_b = (const float*)d_in[4];
  const float* w_w = (const float*)d_in[5];
  const float* w_b = (const float*)d_in[6];
  const float* atten_w = (const float*)d_in[7];
  const float* atten_b = (const float*)d_in[8];
  const float* beta = (const float*)d_in[9];
  const float* lin_w = (const float*)d_in[10];
  const float* lin_b = (const float*)d_in[11];
  float* out = (float*)d_out;

  uint* pck = (uint*)d_ws;                        // RN*64 uints (76.8 MB)
  float* asrc = (float*)(pck + (size_t)RN * 64);  // RN*4
  float* adst = asrc + (size_t)RN * 4;            // RN*4
  int* deg = (int*)(adst + (size_t)RN * 4);       // RN
  int* P = deg + RN;                              // RN
  int* bsums = P + RN;                            // 256
  int* boffs = bsums + 256;                       // 256
  int* rank = boffs + 256;                        // RE
  int* ssrc = rank + RE;                          // RE + 2

  int nb = (RN + 2047) / 2048;
  hipMemsetAsync(deg, 0, RN * sizeof(int), stream);
  k_count<<<(RE + 255) / 256, 256, 0, stream>>>(dst, deg, rank);
  k_scan1<<<nb, 256, 0, stream>>>(deg, P, bsums);
  k_scan2<<<1, 256, 0, stream>>>(bsums, boffs, nb);
  k_scan3<<<(RN + 255) / 256, 256, 0, stream>>>(P, boffs);
  k_scatter<<<(RE + 255) / 256, 256, 0, stream>>>(src, dst, rank, P, ssrc);
  k_node<<<1024, 256, 0, stream>>>(h, d_w, d_b, w_w, w_b, atten_w, atten_b, pck,
                                   asrc, adst);
  k_fused<<<N_NODES / 32, 512, 0, stream>>>(pck, asrc, adst, P, ssrc, beta, lin_w,
                                            lin_b, out);
}